// Round 12
// baseline (164.329 us; speedup 1.0000x reference)
//
#include <hip/hip_runtime.h>
#include <hip/hip_fp16.h>

// GCN 2-layer + classifier, fp32 math, fp16 message buffers.
// R20: SPLIT MESSAGE TABLES (P1a/P1b, P2a/P2b; 3.2MB each < 4MB L2/XCD).
//      Agg kernels run the edge loop twice (compile-time hh loop): pass A
//      gathers only table A (uint2/lane), pass B only table B. Hot gather
//      footprint/pass ~3.2MB -> replicates into every XCD L2 (25.6 < 32MB
//      aggregate) and stays resident; L3/HBM miss churn (R4: 30.8MB FETCH
//      for a 6.4MB table) collapses. Cost: col re-read (L2-hot) + 2x gather
//      issue at half width (~+5us by R10 calibration). Math identical per
//      feature (same edge order) -> absmax unchanged.
// R19: inv folded into P1 (binB pre-scales; -4us, kept). R18: 128-node
//      buckets. R17: pad-16 rows, straight-line loop. R16: padded CSR +
//      packed row_ptr + sentinel row n (tables' row n zeroed).
// CSR-by-dst rebuilt per launch via radix partition, ZERO global atomics.
// Requires n < 65535 (u16 col + sentinel n). Here n=50000, E=800000.

#define FDIM 64
#define NCLS 16
#define TILE 2048
#define BSH 7            // bucket shift: 128 nodes/bucket
#define BSZ 128

// ---- partition pass 1: per-(tile,bucket) histogram + fused layer-1 GEMM ----
__global__ __launch_bounds__(256) void k_histgemm(const int* __restrict__ dst, int E,
                                                  int* __restrict__ H, int nblk,
                                                  const float* __restrict__ X,
                                                  const float* __restrict__ W,
                                                  __half* __restrict__ P1a,
                                                  __half* __restrict__ P1b, int n) {
    __shared__ float Ws[FDIM * FDIM];
    __shared__ int h[512];
    int t = threadIdx.x, blk = blockIdx.x;
    if (blk < nblk) {
        h[t] = 0;
        h[t + 256] = 0;
        __syncthreads();
        int i0 = blk * TILE;
#pragma unroll
        for (int k = 0; k < TILE / 256; ++k) {
            int i = i0 + k * 256 + t;
            if (i < E) atomicAdd(&h[dst[i] >> BSH], 1);
        }
        __syncthreads();
        H[blk * 512 + t] = h[t];           // coalesced
        H[blk * 512 + t + 256] = h[t + 256];
    } else {
        for (int i = t; i < FDIM * FDIM; i += 256) Ws[i] = W[i];
        __syncthreads();
        // zero sentinel row n of P1a/P1b (padded edges gather zeros)
        if (blk == nblk && t < 8) {
            uint4 z = make_uint4(0, 0, 0, 0);
            if (t < 4) ((uint4*)(P1a + (size_t)n * 32))[t] = z;
            else       ((uint4*)(P1b + (size_t)n * 32))[t - 4] = z;
        }
        int idx = (blk - nblk) * 256 + t;
        int row = idx >> 2;
        int cg = (idx & 3) * 16;
        if (row >= n) return;
        const float4* xr = (const float4*)(X + (size_t)row * FDIM);
        float4 xv[16];
#pragma unroll
        for (int i = 0; i < 16; ++i) xv[i] = xr[i];
        float acc[16];
#pragma unroll
        for (int c = 0; c < 16; ++c) acc[c] = 0.f;
#pragma unroll
        for (int i = 0; i < 16; ++i) {
            float xs[4] = {xv[i].x, xv[i].y, xv[i].z, xv[i].w};
#pragma unroll
            for (int j = 0; j < 4; ++j) {
                float xk = xs[j];
                const float* wr = &Ws[(i * 4 + j) * FDIM + cg];
#pragma unroll
                for (int c = 0; c < 16; ++c) acc[c] += xk * wr[c];
            }
        }
        unsigned u[8];
#pragma unroll
        for (int i = 0; i < 8; ++i) {
            __half2 hp = __floats2half2_rn(acc[2 * i], acc[2 * i + 1]);
            u[i] = *(unsigned*)&hp;
        }
        __half* tab = (cg < 32) ? P1a : P1b;
        uint4* yo = (uint4*)(tab + (size_t)row * 32 + (cg & 31));
        yo[0] = make_uint4(u[0], u[1], u[2], u[3]);
        yo[1] = make_uint4(u[4], u[5], u[6], u[7]);
    }
}

// ---- partition pass 2: per-bucket exclusive scan across tiles ----
__global__ __launch_bounds__(512) void k_scanH(int* __restrict__ H, int nblk, int* __restrict__ btot) {
    __shared__ int s[512];
    int t = threadIdx.x, b = blockIdx.x;
    int v = (t < nblk) ? H[t * 512 + b] : 0;
    s[t] = v;
    __syncthreads();
    for (int off = 1; off < 512; off <<= 1) {
        int add = (t >= off) ? s[t - off] : 0;
        __syncthreads();
        s[t] += add;
        __syncthreads();
    }
    if (t < nblk) H[t * 512 + b] = s[t] - v;  // exclusive within bucket
    if (t == 511) btot[b] = s[511];
}

// ---- partition pass 3: scatter packed records into bucket regions ----
__global__ __launch_bounds__(512) void k_scatA(const int* __restrict__ src, const int* __restrict__ dst,
                                               int E, const int* __restrict__ H,
                                               const int* __restrict__ btot, int nb,
                                               unsigned* __restrict__ tmp) {
    __shared__ int s[512];
    __shared__ int Hb[512];
    __shared__ int c2[512];
    int t = threadIdx.x, blk = blockIdx.x;
    int v = (t < nb) ? btot[t] : 0;
    s[t] = v;
    __syncthreads();
    for (int off = 1; off < 512; off <<= 1) {
        int add = (t >= off) ? s[t - off] : 0;
        __syncthreads();
        s[t] += add;
        __syncthreads();
    }
    Hb[t] = (s[t] - v) + H[blk * 512 + t];   // bucket base + tile offset
    c2[t] = 0;
    __syncthreads();
    int i0 = blk * TILE;
#pragma unroll
    for (int k = 0; k < TILE / 512; ++k) {
        int i = i0 + k * 512 + t;
        if (i < E) {
            int sv = src[i], d = dst[i];
            int b = d >> BSH;
            unsigned rec = ((unsigned)(d & (BSZ - 1)) << 16) | (unsigned)sv;
            int pos = Hb[b] + atomicAdd(&c2[b], 1);
            tmp[pos] = rec;
        }
    }
}

// ---- per-bucket CSR finalize + in-place P1a/P1b pre-scale ----
#define COLCAP 6144
__global__ __launch_bounds__(512) void k_binB(const unsigned* __restrict__ tmp,
                                              const int* __restrict__ btot, int nb,
                                              int n, int E, int* __restrict__ row_ptr,
                                              float* __restrict__ inv,
                                              unsigned short* __restrict__ col,
                                              __half* __restrict__ P1a,
                                              __half* __restrict__ P1b) {
    __shared__ int dcnt[BSZ], cur[BSZ], s[512];
    __shared__ float ivS[BSZ];
    __shared__ unsigned short colbuf[COLCAP];
    __shared__ int baseS;
    int t = threadIdx.x, b = blockIdx.x;
    int v = (t < nb) ? btot[t] : 0;
    s[t] = v;
    __syncthreads();
    for (int off = 1; off < 512; off <<= 1) {
        int add = (t >= off) ? s[t - off] : 0;
        __syncthreads();
        s[t] += add;
        __syncthreads();
    }
    if (t == b) baseS = s[t] - v;
    if (t < BSZ) dcnt[t] = 0;
    __syncthreads();
    int base = baseS;
    int pbase = ((base + 7) & ~7) + b * 2048;
    int cntE = btot[b];
    int node0 = b << BSH;
    int nn = min(BSZ, n - node0);
    for (int i = t; i < cntE; i += 512) atomicAdd(&dcnt[tmp[base + i] >> 16], 1);
    __syncthreads();
    int deg = 0, pdeg = 0;
    if (t < BSZ) {
        deg = dcnt[t];
        pdeg = (deg + 15) & ~15;
        s[t] = pdeg;
    }
    __syncthreads();
    for (int off = 1; off < BSZ; off <<= 1) {
        int add = 0;
        if (t < BSZ && t >= off) add = s[t - off];
        __syncthreads();
        if (t < BSZ) s[t] += add;
        __syncthreads();
    }
    int pexcl = (t < BSZ) ? (s[t] - pdeg) : 0;
    int ptot = s[BSZ - 1];
    if (t < BSZ) {
        float ivv = rsqrtf((float)(deg + 1));
        ivS[t] = ivv;
        if (t < nn) {
            row_ptr[node0 + t] = (pbase + pexcl) | ((pdeg >> 4) << 22);
            inv[node0 + t] = ivv;
        }
    }
    if (b == 0 && t == 0) inv[n] = 0.f;
    if (t < BSZ) cur[t] = pexcl;
    __syncthreads();
    for (int i = t; i < cntE; i += 512) {
        unsigned r = tmp[base + i];
        int pos = atomicAdd(&cur[r >> 16], 1);
        unsigned short vv = (unsigned short)(r & 0xFFFFu);
        if (pos < COLCAP) colbuf[pos] = vv;
        else col[pbase + pos] = vv;   // overflow fallback
    }
    // sentinel tail fill (disjoint from scatter range -> no barrier needed)
    if (t < nn) {
        int p1 = pexcl + pdeg;
        for (int p = pexcl + deg; p < p1; ++p) {
            if (p < COLCAP) colbuf[p] = (unsigned short)n;
            else col[pbase + p] = (unsigned short)n;
        }
    }
    __syncthreads();
    int lim = min(ptot, COLCAP);
    for (int i = t; i < lim; i += 512) col[pbase + i] = colbuf[i];
    // ---- in-place pre-scale of this bucket's P1a/P1b rows ----
    {
        int fl = t & 7;
        for (int r = t >> 3; r < nn; r += 64) {
            float ivr = ivS[r];
            uint4* pr;
            if (fl < 4) pr = (uint4*)(P1a + (size_t)(node0 + r) * 32) + fl;
            else        pr = (uint4*)(P1b + (size_t)(node0 + r) * 32) + (fl - 4);
            uint4 q = *pr;
            float2 f0 = __half22float2(*(__half2*)&q.x);
            float2 f1 = __half22float2(*(__half2*)&q.y);
            float2 f2 = __half22float2(*(__half2*)&q.z);
            float2 f3 = __half22float2(*(__half2*)&q.w);
            __half2 h0 = __floats2half2_rn(f0.x * ivr, f0.y * ivr);
            __half2 h1 = __floats2half2_rn(f1.x * ivr, f1.y * ivr);
            __half2 h2 = __floats2half2_rn(f2.x * ivr, f2.y * ivr);
            __half2 h3 = __floats2half2_rn(f3.x * ivr, f3.y * ivr);
            *pr = make_uint4(*(unsigned*)&h0, *(unsigned*)&h1,
                             *(unsigned*)&h2, *(unsigned*)&h3);
        }
    }
}

__device__ __forceinline__ void unpack4(const uint2& q, float* f) {
    float2 f0 = __half22float2(*(const __half2*)&q.x);
    float2 f1 = __half22float2(*(const __half2*)&q.y);
    f[0] = f0.x; f[1] = f0.y; f[2] = f1.x; f[3] = f1.y;
}
__device__ __forceinline__ void decode8(const uint4& cv, int* c) {
    c[0] = cv.x & 0xFFFF; c[1] = cv.x >> 16;
    c[2] = cv.y & 0xFFFF; c[3] = cv.y >> 16;
    c[4] = cv.z & 0xFFFF; c[5] = cv.z >> 16;
    c[6] = cv.w & 0xFFFF; c[7] = cv.w >> 16;
}

// ---- agg layer 1 (pre-scaled tables, two L2-resident passes) + W2 GEMM ----
// Pass hh gathers ONLY table hh (3.2MB): lane fl reads uint2 (features
// fb=hh*32+fl*4 .. +3); 8 lanes/node cover the 64B half-row. Accumulate
// a4, epilogue relu(iv*a4+b) into rbuf[.][fb..]. Phase B unchanged;
// P2 written split (cg<4 -> P2a, else P2b).
__global__ __launch_bounds__(256) void k_aggF1(const __half* __restrict__ P1a, const __half* __restrict__ P1b,
                                               const float* __restrict__ inv,
                                               const int* __restrict__ row_ptr,
                                               const unsigned short* __restrict__ col,
                                               const float* __restrict__ bias,
                                               const float* __restrict__ W2,
                                               __half* __restrict__ P2a, __half* __restrict__ P2b, int n) {
    __shared__ float W2s[FDIM * FDIM];
    __shared__ float rbuf[32][FDIM + 1];
    int t0 = threadIdx.x;
    for (int i = t0; i < FDIM * FDIM; i += 256) W2s[i] = W2[i];
    // zero sentinel rows n of P2a/P2b for aggF2
    if (blockIdx.x == 0 && t0 < 8) {
        uint4 z = make_uint4(0, 0, 0, 0);
        if (t0 < 4) ((uint4*)(P2a + (size_t)n * 32))[t0] = z;
        else        ((uint4*)(P2b + (size_t)n * 32))[t0 - 4] = z;
    }
    int lane = t0 & 63;
    int sub = lane >> 3;      // node-in-wave 0..7
    int fl = lane & 7;        // feature quad 0..7 within half
    int wid = t0 >> 6;
    int nl = wid * 8 + sub;   // local node 0..31
    int node = blockIdx.x * 32 + nl;
    bool alive = node < n;
    int nodeC = alive ? node : (n - 1);
    float iv = inv[nodeC];
    int v = row_ptr[nodeC];
    int s = v & 0x3FFFFF;
    int e = alive ? s + ((v >> 22) << 4) : s;
#pragma unroll
    for (int hh = 0; hh < 2; ++hh) {
        const uint2* Pq2 = (const uint2*)(hh ? P1b : P1a);
        uint2 selfq = Pq2[(size_t)nodeC * 8 + fl];
        float a4[4], f4[4];
        unpack4(selfq, a4);   // self term (pre-scaled)
        for (int j = s; j < e; j += 16) {
            uint4 cv0 = *(const uint4*)(col + j);
            uint4 cv1 = *(const uint4*)(col + j + 8);
            int c[16];
            decode8(cv0, c);
            decode8(cv1, c + 8);
            uint2 q[16];
#pragma unroll
            for (int k = 0; k < 16; ++k) q[k] = Pq2[(size_t)c[k] * 8 + fl];
#pragma unroll
            for (int k = 0; k < 16; ++k) {
                unpack4(q[k], f4);
#pragma unroll
                for (int i = 0; i < 4; ++i) a4[i] += f4[i];   // sentinel = zeros
            }
        }
        int fb = hh * 32 + fl * 4;
        float4 bb = ((const float4*)bias)[fb >> 2];
        rbuf[nl][fb + 0] = fmaxf(fmaf(iv, a4[0], bb.x), 0.f);
        rbuf[nl][fb + 1] = fmaxf(fmaf(iv, a4[1], bb.y), 0.f);
        rbuf[nl][fb + 2] = fmaxf(fmaf(iv, a4[2], bb.z), 0.f);
        rbuf[nl][fb + 3] = fmaxf(fmaf(iv, a4[3], bb.w), 0.f);
    }
    __syncthreads();   // covers W2s load too
    // Phase B: 256 threads = 32 nodes x 8 col-octets
    int nl2 = t0 >> 3;
    int cg = t0 & 7;
    int node2 = blockIdx.x * 32 + nl2;
    const float* rr = rbuf[nl2];
    float o[8];
#pragma unroll
    for (int i = 0; i < 8; ++i) o[i] = 0.f;
#pragma unroll
    for (int i = 0; i < FDIM; ++i) {
        float xk = rr[i];
        const float* wv = &W2s[i * FDIM + cg * 8];
#pragma unroll
        for (int c = 0; c < 8; ++c) o[c] = fmaf(xk, wv[c], o[c]);
    }
    if (node2 < n) {
        float iv2 = inv[node2];
        unsigned u[4];
#pragma unroll
        for (int i = 0; i < 4; ++i) {
            __half2 hp = __floats2half2_rn(o[2 * i] * iv2, o[2 * i + 1] * iv2);
            u[i] = *(unsigned*)&hp;
        }
        uint4 val = make_uint4(u[0], u[1], u[2], u[3]);
        if (cg < 4) ((uint4*)(P2a + (size_t)node2 * 32))[cg] = val;
        else        ((uint4*)(P2b + (size_t)node2 * 32))[cg - 4] = val;
    }
}

// ---- agg layer 2 (two L2-resident passes) + fused classifier ----
__global__ __launch_bounds__(256) void k_aggF2(const __half* __restrict__ P2a, const __half* __restrict__ P2b,
                                               const float* __restrict__ inv,
                                               const int* __restrict__ row_ptr,
                                               const unsigned short* __restrict__ col,
                                               const float* __restrict__ bias,
                                               const float* __restrict__ Wc, const float* __restrict__ bc,
                                               float* __restrict__ out, int n) {
    __shared__ float WcT[NCLS * FDIM];   // transposed: WcT[c*64+f]
    int t0 = threadIdx.x;
    for (int i = t0; i < FDIM * NCLS; i += 256) {
        int c = i & 15, ff = i >> 4;
        WcT[c * FDIM + ff] = Wc[i];
    }
    __syncthreads();
    int lane = t0 & 63;
    int sub = lane >> 3;
    int fl = lane & 7;
    int wid = t0 >> 6;
    int node = blockIdx.x * 32 + wid * 8 + sub;
    bool alive = node < n;
    int nodeC = alive ? node : (n - 1);
    float iv = inv[nodeC];
    int v = row_ptr[nodeC];
    int s = v & 0x3FFFFF;
    int e = alive ? s + ((v >> 22) << 4) : s;
    float part[NCLS];
#pragma unroll
    for (int c = 0; c < NCLS; ++c) part[c] = 0.f;
#pragma unroll
    for (int hh = 0; hh < 2; ++hh) {
        const uint2* Pq2 = (const uint2*)(hh ? P2b : P2a);
        uint2 selfq = Pq2[(size_t)nodeC * 8 + fl];
        float a4[4], f4[4];
        unpack4(selfq, a4);
        for (int j = s; j < e; j += 16) {
            uint4 cv0 = *(const uint4*)(col + j);
            uint4 cv1 = *(const uint4*)(col + j + 8);
            int c[16];
            decode8(cv0, c);
            decode8(cv1, c + 8);
            uint2 q[16];
#pragma unroll
            for (int k = 0; k < 16; ++k) q[k] = Pq2[(size_t)c[k] * 8 + fl];
#pragma unroll
            for (int k = 0; k < 16; ++k) {
                unpack4(q[k], f4);
#pragma unroll
                for (int i = 0; i < 4; ++i) a4[i] += f4[i];   // sentinel = zeros
            }
        }
        int fb = hh * 32 + fl * 4;
        float4 bb = ((const float4*)bias)[fb >> 2];
        float r0 = fmaxf(fmaf(iv, a4[0], bb.x), 0.f);
        float r1 = fmaxf(fmaf(iv, a4[1], bb.y), 0.f);
        float r2 = fmaxf(fmaf(iv, a4[2], bb.z), 0.f);
        float r3 = fmaxf(fmaf(iv, a4[3], bb.w), 0.f);
#pragma unroll
        for (int c = 0; c < NCLS; ++c) {
            float4 wv = *(const float4*)(WcT + c * FDIM + fb);
            part[c] = fmaf(r0, wv.x, part[c]);
            part[c] = fmaf(r1, wv.y, part[c]);
            part[c] = fmaf(r2, wv.z, part[c]);
            part[c] = fmaf(r3, wv.w, part[c]);
        }
    }
#pragma unroll
    for (int m = 1; m < 8; m <<= 1) {
#pragma unroll
        for (int c = 0; c < NCLS; ++c) part[c] += __shfl_xor(part[c], m, 64);
    }
    if (alive && fl < 4) {
        float4 bb2 = ((const float4*)bc)[fl];
        float4 o = make_float4(part[fl * 4 + 0] + bb2.x, part[fl * 4 + 1] + bb2.y,
                               part[fl * 4 + 2] + bb2.z, part[fl * 4 + 3] + bb2.w);
        ((float4*)out)[(size_t)node * 4 + fl] = o;
    }
}

static inline size_t align256(size_t x) { return (x + 255) & ~(size_t)255; }

extern "C" void kernel_launch(void* const* d_in, const int* in_sizes, int n_in,
                              void* d_out, int out_size, void* d_ws, size_t ws_size,
                              hipStream_t stream) {
    const float* x  = (const float*)d_in[0];
    const int*   ei = (const int*)d_in[1];
    const float* W1 = (const float*)d_in[2];
    const float* b1 = (const float*)d_in[3];
    const float* W2 = (const float*)d_in[4];
    const float* b2 = (const float*)d_in[5];
    const float* Wc = (const float*)d_in[6];
    const float* bc = (const float*)d_in[7];
    float* out = (float*)d_out;

    const int n = in_sizes[0] / FDIM;   // 50000
    const int E = in_sizes[1] / 2;      // 800000
    const int* src = ei;
    const int* dst = ei + E;

    const int nb = (n + BSZ - 1) >> BSH;      // 391 buckets (128 nodes each)
    const int nblk = (E + TILE - 1) / TILE;   // 391 tiles

    // workspace carve-up (split half-feature tables, +1 sentinel row each)
    char* w = (char*)d_ws;
    size_t off = 0;
    int* H = (int*)(w + off);        off = align256(off + (size_t)nblk * 512 * 4);
    int* btot = (int*)(w + off);     off = align256(off + 512 * 4);
    int* row_ptr = (int*)(w + off);  off = align256(off + (size_t)(n + 1) * 4);
    float* inv = (float*)(w + off);  off = align256(off + (size_t)(n + 1) * 4);
    unsigned* tmp = (unsigned*)(w + off);             off = align256(off + (size_t)E * 4);
    unsigned short* col = (unsigned short*)(w + off); off = align256(off + ((size_t)E + (size_t)nb * 2048 + 128) * 2);
    __half* P1a = (__half*)(w + off); off = align256(off + (size_t)(n + 1) * 32 * 2);
    __half* P1b = (__half*)(w + off); off = align256(off + (size_t)(n + 1) * 32 * 2);
    __half* P2a = (__half*)(w + off); off = align256(off + (size_t)(n + 1) * 32 * 2);
    __half* P2b = (__half*)(w + off); off = align256(off + (size_t)(n + 1) * 32 * 2);
    (void)ws_size;

    const int nbG = (n * 4 + 255) / 256;
    const int nbA = (n + 31) / 32;     // 32 nodes per block

    // CSR build + fused layer-1 GEMM riding along (writes split P1a/P1b)
    k_histgemm<<<nblk + nbG, 256, 0, stream>>>(dst, E, H, nblk, x, W1, P1a, P1b, n);
    k_scanH<<<nb, 512, 0, stream>>>(H, nblk, btot);
    k_scatA<<<nblk, 512, 0, stream>>>(src, dst, E, H, btot, nb, tmp);
    // binB also pre-scales P1a/P1b in place (P1s = inv * h)
    k_binB<<<nb, 512, 0, stream>>>(tmp, btot, nb, n, E, row_ptr, inv, col, P1a, P1b);

    // layer 1 agg (two L2-resident passes) + fused W2 GEMM -> P2a/P2b
    k_aggF1<<<nbA, 256, 0, stream>>>(P1a, P1b, inv, row_ptr, col, b1, W2, P2a, P2b, n);
    // layer 2 agg (two L2-resident passes) + fused classifier
    k_aggF2<<<nbA, 256, 0, stream>>>(P2a, P2b, inv, row_ptr, col, b2, Wc, bc, out, n);
}

// Round 13
// 151.093 us; speedup vs baseline: 1.0876x; 1.0876x over previous
//
#include <hip/hip_runtime.h>
#include <hip/hip_fp16.h>

// GCN 2-layer + classifier, fp32 math, fp16 message buffers.
// R21: REVERT to R19 (151.7us best) + NON-TEMPORAL col loads in aggs.
//      R20 (split tables) regressed +12.6: half-width gathers doubled
//      per-edge line requests. nt col loads attack the same L2-capacity
//      mechanism (streaming col evicts gather-table lines) at zero extra
//      request cost. Ledger R9-R20: only real win = R19 inv-fold (-4us);
//      aggs are at the random-128B-gather service-rate floor (~2.6 TB/s
//      effective) -- bytes/issue/chain/MLP/TLP/skew/capacity all nulled.
// R19: inv folded into P1 (binB pre-scales in place; aggF1 weight-free).
// R18: 128-node buckets. R17: pad-16 rows + straight-line 16-edge loop.
// R16: padded CSR + packed row_ptr + sentinel row n (P1/P2[n]=0, inv[n]=0).
// R10: 8 lanes/node uint4 gathers. R9: gemm fused in histgemm.
// CSR-by-dst rebuilt per launch via radix partition, ZERO global atomics.
// Requires n < 65535 (u16 col + sentinel n). Here n=50000, E=800000.

#define FDIM 64
#define NCLS 16
#define TILE 2048
#define BSH 7            // bucket shift: 128 nodes/bucket
#define BSZ 128

// ---- partition pass 1: per-(tile,bucket) histogram + fused layer-1 GEMM ----
__global__ __launch_bounds__(256) void k_histgemm(const int* __restrict__ dst, int E,
                                                  int* __restrict__ H, int nblk,
                                                  const float* __restrict__ X,
                                                  const float* __restrict__ W,
                                                  __half* __restrict__ Yh, int n) {
    __shared__ float Ws[FDIM * FDIM];
    __shared__ int h[512];
    int t = threadIdx.x, blk = blockIdx.x;
    if (blk < nblk) {
        h[t] = 0;
        h[t + 256] = 0;
        __syncthreads();
        int i0 = blk * TILE;
#pragma unroll
        for (int k = 0; k < TILE / 256; ++k) {
            int i = i0 + k * 256 + t;
            if (i < E) atomicAdd(&h[dst[i] >> BSH], 1);
        }
        __syncthreads();
        H[blk * 512 + t] = h[t];           // coalesced
        H[blk * 512 + t + 256] = h[t + 256];
    } else {
        for (int i = t; i < FDIM * FDIM; i += 256) Ws[i] = W[i];
        __syncthreads();
        // zero sentinel row n of P1 (padded edges gather it with weight 0)
        if (blk == nblk && t < 8)
            ((uint4*)Yh)[(size_t)n * 8 + t] = make_uint4(0, 0, 0, 0);
        int idx = (blk - nblk) * 256 + t;
        int row = idx >> 2;
        int cg = (idx & 3) * 16;
        if (row >= n) return;
        const float4* xr = (const float4*)(X + (size_t)row * FDIM);
        float4 xv[16];
#pragma unroll
        for (int i = 0; i < 16; ++i) xv[i] = xr[i];
        float acc[16];
#pragma unroll
        for (int c = 0; c < 16; ++c) acc[c] = 0.f;
#pragma unroll
        for (int i = 0; i < 16; ++i) {
            float xs[4] = {xv[i].x, xv[i].y, xv[i].z, xv[i].w};
#pragma unroll
            for (int j = 0; j < 4; ++j) {
                float xk = xs[j];
                const float* wr = &Ws[(i * 4 + j) * FDIM + cg];
#pragma unroll
                for (int c = 0; c < 16; ++c) acc[c] += xk * wr[c];
            }
        }
        unsigned u[8];
#pragma unroll
        for (int i = 0; i < 8; ++i) {
            __half2 hp = __floats2half2_rn(acc[2 * i], acc[2 * i + 1]);
            u[i] = *(unsigned*)&hp;
        }
        uint4* yo = (uint4*)(Yh + (size_t)row * FDIM + cg);
        yo[0] = make_uint4(u[0], u[1], u[2], u[3]);
        yo[1] = make_uint4(u[4], u[5], u[6], u[7]);
    }
}

// ---- partition pass 2: per-bucket exclusive scan across tiles ----
__global__ __launch_bounds__(512) void k_scanH(int* __restrict__ H, int nblk, int* __restrict__ btot) {
    __shared__ int s[512];
    int t = threadIdx.x, b = blockIdx.x;
    int v = (t < nblk) ? H[t * 512 + b] : 0;
    s[t] = v;
    __syncthreads();
    for (int off = 1; off < 512; off <<= 1) {
        int add = (t >= off) ? s[t - off] : 0;
        __syncthreads();
        s[t] += add;
        __syncthreads();
    }
    if (t < nblk) H[t * 512 + b] = s[t] - v;  // exclusive within bucket
    if (t == 511) btot[b] = s[511];
}

// ---- partition pass 3: scatter packed records into bucket regions ----
__global__ __launch_bounds__(512) void k_scatA(const int* __restrict__ src, const int* __restrict__ dst,
                                               int E, const int* __restrict__ H,
                                               const int* __restrict__ btot, int nb,
                                               unsigned* __restrict__ tmp) {
    __shared__ int s[512];
    __shared__ int Hb[512];
    __shared__ int c2[512];
    int t = threadIdx.x, blk = blockIdx.x;
    int v = (t < nb) ? btot[t] : 0;
    s[t] = v;
    __syncthreads();
    for (int off = 1; off < 512; off <<= 1) {
        int add = (t >= off) ? s[t - off] : 0;
        __syncthreads();
        s[t] += add;
        __syncthreads();
    }
    Hb[t] = (s[t] - v) + H[blk * 512 + t];   // bucket base + tile offset
    c2[t] = 0;
    __syncthreads();
    int i0 = blk * TILE;
#pragma unroll
    for (int k = 0; k < TILE / 512; ++k) {
        int i = i0 + k * 512 + t;
        if (i < E) {
            int sv = src[i], d = dst[i];
            int b = d >> BSH;
            unsigned rec = ((unsigned)(d & (BSZ - 1)) << 16) | (unsigned)sv;
            int pos = Hb[b] + atomicAdd(&c2[b], 1);
            tmp[pos] = rec;
        }
    }
}

// ---- per-bucket CSR finalize + in-place P1 pre-scale ----
// pbase = align8(base) + b*2048; rows padded to x16; row_ptr = start|(pdeg/16)<<22.
// After inv computed, scale this bucket's P1 rows in place: P1[r] *= inv[r].
#define COLCAP 6144
__global__ __launch_bounds__(512) void k_binB(const unsigned* __restrict__ tmp,
                                              const int* __restrict__ btot, int nb,
                                              int n, int E, int* __restrict__ row_ptr,
                                              float* __restrict__ inv,
                                              unsigned short* __restrict__ col,
                                              __half* __restrict__ P1) {
    __shared__ int dcnt[BSZ], cur[BSZ], s[512];
    __shared__ float ivS[BSZ];
    __shared__ unsigned short colbuf[COLCAP];
    __shared__ int baseS;
    int t = threadIdx.x, b = blockIdx.x;
    int v = (t < nb) ? btot[t] : 0;
    s[t] = v;
    __syncthreads();
    for (int off = 1; off < 512; off <<= 1) {
        int add = (t >= off) ? s[t - off] : 0;
        __syncthreads();
        s[t] += add;
        __syncthreads();
    }
    if (t == b) baseS = s[t] - v;
    if (t < BSZ) dcnt[t] = 0;
    __syncthreads();
    int base = baseS;
    int pbase = ((base + 7) & ~7) + b * 2048;
    int cntE = btot[b];
    int node0 = b << BSH;
    int nn = min(BSZ, n - node0);
    for (int i = t; i < cntE; i += 512) atomicAdd(&dcnt[tmp[base + i] >> 16], 1);
    __syncthreads();
    int deg = 0, pdeg = 0;
    if (t < BSZ) {
        deg = dcnt[t];
        pdeg = (deg + 15) & ~15;
        s[t] = pdeg;
    }
    __syncthreads();
    for (int off = 1; off < BSZ; off <<= 1) {
        int add = 0;
        if (t < BSZ && t >= off) add = s[t - off];
        __syncthreads();
        if (t < BSZ) s[t] += add;
        __syncthreads();
    }
    int pexcl = (t < BSZ) ? (s[t] - pdeg) : 0;
    int ptot = s[BSZ - 1];
    if (t < BSZ) {
        float ivv = rsqrtf((float)(deg + 1));
        ivS[t] = ivv;
        if (t < nn) {
            row_ptr[node0 + t] = (pbase + pexcl) | ((pdeg >> 4) << 22);
            inv[node0 + t] = ivv;
        }
    }
    if (b == 0 && t == 0) inv[n] = 0.f;   // sentinel weight (unused now, kept)
    if (t < BSZ) cur[t] = pexcl;
    __syncthreads();
    for (int i = t; i < cntE; i += 512) {
        unsigned r = tmp[base + i];
        int pos = atomicAdd(&cur[r >> 16], 1);
        unsigned short vv = (unsigned short)(r & 0xFFFFu);
        if (pos < COLCAP) colbuf[pos] = vv;
        else col[pbase + pos] = vv;   // overflow fallback
    }
    // sentinel tail fill (disjoint from scatter range -> no barrier needed)
    if (t < nn) {
        int p1 = pexcl + pdeg;
        for (int p = pexcl + deg; p < p1; ++p) {
            if (p < COLCAP) colbuf[p] = (unsigned short)n;
            else col[pbase + p] = (unsigned short)n;
        }
    }
    __syncthreads();
    int lim = min(ptot, COLCAP);
    for (int i = t; i < lim; i += 512) col[pbase + i] = colbuf[i];
    // ---- in-place pre-scale of this bucket's P1 rows ----
    {
        int fl = t & 7;
        for (int r = t >> 3; r < nn; r += 64) {
            float ivr = ivS[r];
            uint4* pr = (uint4*)P1 + (size_t)(node0 + r) * 8 + fl;
            uint4 q = *pr;
            float2 f0 = __half22float2(*(__half2*)&q.x);
            float2 f1 = __half22float2(*(__half2*)&q.y);
            float2 f2 = __half22float2(*(__half2*)&q.z);
            float2 f3 = __half22float2(*(__half2*)&q.w);
            __half2 h0 = __floats2half2_rn(f0.x * ivr, f0.y * ivr);
            __half2 h1 = __floats2half2_rn(f1.x * ivr, f1.y * ivr);
            __half2 h2 = __floats2half2_rn(f2.x * ivr, f2.y * ivr);
            __half2 h3 = __floats2half2_rn(f3.x * ivr, f3.y * ivr);
            *pr = make_uint4(*(unsigned*)&h0, *(unsigned*)&h1,
                             *(unsigned*)&h2, *(unsigned*)&h3);
        }
    }
}

__device__ __forceinline__ void unpack8(const uint4& q, float* f) {
    float2 f0 = __half22float2(*(const __half2*)&q.x);
    float2 f1 = __half22float2(*(const __half2*)&q.y);
    float2 f2 = __half22float2(*(const __half2*)&q.z);
    float2 f3 = __half22float2(*(const __half2*)&q.w);
    f[0] = f0.x; f[1] = f0.y; f[2] = f1.x; f[3] = f1.y;
    f[4] = f2.x; f[5] = f2.y; f[6] = f3.x; f[7] = f3.y;
}
__device__ __forceinline__ void decode8(const uint4& cv, int* c) {
    c[0] = cv.x & 0xFFFF; c[1] = cv.x >> 16;
    c[2] = cv.y & 0xFFFF; c[3] = cv.y >> 16;
    c[4] = cv.z & 0xFFFF; c[5] = cv.z >> 16;
    c[6] = cv.w & 0xFFFF; c[7] = cv.w >> 16;
}
// non-temporal 16B load of 8 u16 cols (streaming, don't pollute L2)
typedef unsigned int u32x4 __attribute__((ext_vector_type(4)));
__device__ __forceinline__ uint4 ntload_cols(const unsigned short* p) {
    u32x4 v = __builtin_nontemporal_load((const u32x4*)p);
    return make_uint4(v.x, v.y, v.z, v.w);
}

// ---- agg layer 1 (P1 pre-scaled -> weight-free) + fused W2 GEMM -> P2 ----
// Unconditional adds, no inv gathers; col read non-temporal (R21).
__global__ __launch_bounds__(256) void k_aggF1(const __half* __restrict__ Ph, const float* __restrict__ inv,
                                               const int* __restrict__ row_ptr,
                                               const unsigned short* __restrict__ col,
                                               const float* __restrict__ bias,
                                               const float* __restrict__ W2,
                                               __half* __restrict__ P2, int n) {
    __shared__ float W2s[FDIM * FDIM];
    __shared__ float rbuf[32][FDIM + 1];
    int t0 = threadIdx.x;
    for (int i = t0; i < FDIM * FDIM; i += 256) W2s[i] = W2[i];
    // zero sentinel row n of P2 for aggF2
    if (blockIdx.x == 0 && t0 < 8)
        ((uint4*)P2)[(size_t)n * 8 + t0] = make_uint4(0, 0, 0, 0);
    int lane = t0 & 63;
    int sub = lane >> 3;      // node-in-wave 0..7
    int fl = lane & 7;        // feature octet 0..7
    int wid = t0 >> 6;
    int nl = wid * 8 + sub;   // local node 0..31
    int node = blockIdx.x * 32 + nl;
    bool alive = node < n;
    int nodeC = alive ? node : (n - 1);
    float iv = inv[nodeC];
    const uint4* Pq = (const uint4*)Ph;
    uint4 selfq = Pq[(size_t)nodeC * 8 + fl];
    float a[8], f[8];
    unpack8(selfq, a);        // self term: P1s[d] = iv_d * h_d (pre-scaled)
    int v = row_ptr[nodeC];
    int s = v & 0x3FFFFF;
    int e = alive ? s + ((v >> 22) << 4) : s;
    for (int j = s; j < e; j += 16) {
        uint4 cv0 = ntload_cols(col + j);       // 8 cols, nt
        uint4 cv1 = ntload_cols(col + j + 8);   // 8 cols, nt
        int c[16];
        decode8(cv0, c);
        decode8(cv1, c + 8);
        uint4 q[16];
#pragma unroll
        for (int k = 0; k < 16; ++k) q[k] = Pq[(size_t)c[k] * 8 + fl];
#pragma unroll
        for (int k = 0; k < 16; ++k) {
            unpack8(q[k], f);
#pragma unroll
            for (int i = 0; i < 8; ++i) a[i] += f[i];   // sentinel row = zeros
        }
    }
    float4 bb0 = ((const float4*)bias)[fl * 2];
    float4 bb1 = ((const float4*)bias)[fl * 2 + 1];
    float bbv[8] = {bb0.x, bb0.y, bb0.z, bb0.w, bb1.x, bb1.y, bb1.z, bb1.w};
#pragma unroll
    for (int i = 0; i < 8; ++i)
        rbuf[nl][fl * 8 + i] = fmaxf(fmaf(iv, a[i], bbv[i]), 0.f);
    __syncthreads();   // covers W2s load too
    // Phase B: 256 threads = 32 nodes x 8 col-octets
    int nl2 = t0 >> 3;
    int cg = t0 & 7;
    int node2 = blockIdx.x * 32 + nl2;
    const float* rr = rbuf[nl2];
    float o[8];
#pragma unroll
    for (int i = 0; i < 8; ++i) o[i] = 0.f;
#pragma unroll
    for (int i = 0; i < FDIM; ++i) {
        float xk = rr[i];
        const float* wv = &W2s[i * FDIM + cg * 8];
#pragma unroll
        for (int c = 0; c < 8; ++c) o[c] = fmaf(xk, wv[c], o[c]);
    }
    if (node2 < n) {
        float iv2 = inv[node2];
        unsigned u[4];
#pragma unroll
        for (int i = 0; i < 4; ++i) {
            __half2 hp = __floats2half2_rn(o[2 * i] * iv2, o[2 * i + 1] * iv2);
            u[i] = *(unsigned*)&hp;
        }
        ((uint4*)P2)[(size_t)node2 * 8 + cg] = make_uint4(u[0], u[1], u[2], u[3]);
    }
}

// ---- agg layer 2 + fused classifier (P2 pre-scaled -> weight-free) ----
__global__ __launch_bounds__(256) void k_aggF2(const __half* __restrict__ Ph, const float* __restrict__ inv,
                                               const int* __restrict__ row_ptr,
                                               const unsigned short* __restrict__ col,
                                               const float* __restrict__ bias,
                                               const float* __restrict__ Wc, const float* __restrict__ bc,
                                               float* __restrict__ out, int n) {
    __shared__ float WcT[NCLS * FDIM];   // transposed: WcT[c*64+f]
    int t0 = threadIdx.x;
    for (int i = t0; i < FDIM * NCLS; i += 256) {
        int c = i & 15, ff = i >> 4;
        WcT[c * FDIM + ff] = Wc[i];
    }
    __syncthreads();
    int lane = t0 & 63;
    int sub = lane >> 3;
    int fl = lane & 7;
    int wid = t0 >> 6;
    int node = blockIdx.x * 32 + wid * 8 + sub;
    bool alive = node < n;
    int nodeC = alive ? node : (n - 1);
    float iv = inv[nodeC];
    const uint4* Pq = (const uint4*)Ph;
    uint4 selfq = Pq[(size_t)nodeC * 8 + fl];
    float a[8], f[8];
    unpack8(selfq, a);
    int v = row_ptr[nodeC];
    int s = v & 0x3FFFFF;
    int e = alive ? s + ((v >> 22) << 4) : s;
    for (int j = s; j < e; j += 16) {
        uint4 cv0 = ntload_cols(col + j);
        uint4 cv1 = ntload_cols(col + j + 8);
        int c[16];
        decode8(cv0, c);
        decode8(cv1, c + 8);
        uint4 q[16];
#pragma unroll
        for (int k = 0; k < 16; ++k) q[k] = Pq[(size_t)c[k] * 8 + fl];
#pragma unroll
        for (int k = 0; k < 16; ++k) {
            unpack8(q[k], f);
#pragma unroll
            for (int i = 0; i < 8; ++i) a[i] += f[i];   // sentinel row = zeros
        }
    }
    float4 bb0 = ((const float4*)bias)[fl * 2];
    float4 bb1 = ((const float4*)bias)[fl * 2 + 1];
    float bbv[8] = {bb0.x, bb0.y, bb0.z, bb0.w, bb1.x, bb1.y, bb1.z, bb1.w};
    float r[8];
#pragma unroll
    for (int i = 0; i < 8; ++i) r[i] = fmaxf(fmaf(iv, a[i], bbv[i]), 0.f);
    float part[NCLS];
#pragma unroll
    for (int c = 0; c < NCLS; ++c) {
        float4 wv0 = ((const float4*)(WcT + c * FDIM))[fl * 2];
        float4 wv1 = ((const float4*)(WcT + c * FDIM))[fl * 2 + 1];
        part[c] = r[0] * wv0.x;
        part[c] = fmaf(r[1], wv0.y, part[c]);
        part[c] = fmaf(r[2], wv0.z, part[c]);
        part[c] = fmaf(r[3], wv0.w, part[c]);
        part[c] = fmaf(r[4], wv1.x, part[c]);
        part[c] = fmaf(r[5], wv1.y, part[c]);
        part[c] = fmaf(r[6], wv1.z, part[c]);
        part[c] = fmaf(r[7], wv1.w, part[c]);
    }
#pragma unroll
    for (int m = 1; m < 8; m <<= 1) {
#pragma unroll
        for (int c = 0; c < NCLS; ++c) part[c] += __shfl_xor(part[c], m, 64);
    }
    if (alive && fl < 4) {
        float4 bb2 = ((const float4*)bc)[fl];
        float4 o = make_float4(part[fl * 4 + 0] + bb2.x, part[fl * 4 + 1] + bb2.y,
                               part[fl * 4 + 2] + bb2.z, part[fl * 4 + 3] + bb2.w);
        ((float4*)out)[(size_t)node * 4 + fl] = o;
    }
}

static inline size_t align256(size_t x) { return (x + 255) & ~(size_t)255; }

extern "C" void kernel_launch(void* const* d_in, const int* in_sizes, int n_in,
                              void* d_out, int out_size, void* d_ws, size_t ws_size,
                              hipStream_t stream) {
    const float* x  = (const float*)d_in[0];
    const int*   ei = (const int*)d_in[1];
    const float* W1 = (const float*)d_in[2];
    const float* b1 = (const float*)d_in[3];
    const float* W2 = (const float*)d_in[4];
    const float* b2 = (const float*)d_in[5];
    const float* Wc = (const float*)d_in[6];
    const float* bc = (const float*)d_in[7];
    float* out = (float*)d_out;

    const int n = in_sizes[0] / FDIM;   // 50000
    const int E = in_sizes[1] / 2;      // 800000
    const int* src = ei;
    const int* dst = ei + E;

    const int nb = (n + BSZ - 1) >> BSH;      // 391 buckets (128 nodes each)
    const int nblk = (E + TILE - 1) / TILE;   // 391 tiles

    // workspace carve-up (inv/P1/P2 have +1 sentinel entry/row; col padded x16)
    char* w = (char*)d_ws;
    size_t off = 0;
    int* H = (int*)(w + off);        off = align256(off + (size_t)nblk * 512 * 4);
    int* btot = (int*)(w + off);     off = align256(off + 512 * 4);
    int* row_ptr = (int*)(w + off);  off = align256(off + (size_t)(n + 1) * 4);
    float* inv = (float*)(w + off);  off = align256(off + (size_t)(n + 1) * 4);
    unsigned* tmp = (unsigned*)(w + off);             off = align256(off + (size_t)E * 4);
    unsigned short* col = (unsigned short*)(w + off); off = align256(off + ((size_t)E + (size_t)nb * 2048 + 128) * 2);
    __half* P1 = (__half*)(w + off); off = align256(off + (size_t)(n + 1) * FDIM * 2);
    __half* P2 = (__half*)(w + off); off = align256(off + (size_t)(n + 1) * FDIM * 2);
    (void)ws_size;

    const int nbG = (n * 4 + 255) / 256;
    const int nbA = (n + 31) / 32;     // 32 nodes per block

    // CSR build + fused layer-1 GEMM riding along
    k_histgemm<<<nblk + nbG, 256, 0, stream>>>(dst, E, H, nblk, x, W1, P1, n);
    k_scanH<<<nb, 512, 0, stream>>>(H, nblk, btot);
    k_scatA<<<nblk, 512, 0, stream>>>(src, dst, E, H, btot, nb, tmp);
    // binB also pre-scales P1 in place (P1s = inv * h)
    k_binB<<<nb, 512, 0, stream>>>(tmp, btot, nb, n, E, row_ptr, inv, col, P1);

    // layer 1 agg (P1 pre-scaled, weight-free) + fused W2 GEMM -> P2
    k_aggF1<<<nbA, 256, 0, stream>>>(P1, inv, row_ptr, col, b1, W2, P2, n);
    // layer 2 agg + fused classifier
    k_aggF2<<<nbA, 256, 0, stream>>>(P2, inv, row_ptr, col, b2, Wc, bc, out, n);
}